// Round 1
// baseline (629.527 us; speedup 1.0000x reference)
//
#include <hip/hip_runtime.h>
#include <hip/hip_fp16.h>

#define NNODES 50000
#define NEDGES 800000

typedef _Float16 f16;
typedef f16 f16x8 __attribute__((ext_vector_type(8)));
typedef float f32x4 __attribute__((ext_vector_type(4)));

// ---------------- utility kernels ----------------

__global__ void k_cvt(const float* __restrict__ s, f16* __restrict__ d, int n) {
    int i = blockIdx.x * blockDim.x + threadIdx.x;
    int stride = gridDim.x * blockDim.x;
    for (; i < n; i += stride) d[i] = (f16)s[i];
}

__global__ void k_deg(const int* __restrict__ dst, int* __restrict__ deg, int E) {
    int i = blockIdx.x * blockDim.x + threadIdx.x;
    int stride = gridDim.x * blockDim.x;
    for (; i < E; i += stride) atomicAdd(&deg[dst[i]], 1);
}

// per-block sums of deg (256 per block)
__global__ void k_bsum(const int* __restrict__ deg, int* __restrict__ bsum, int n) {
    __shared__ int s[256];
    int i = blockIdx.x * 256 + threadIdx.x;
    s[threadIdx.x] = (i < n) ? deg[i] : 0;
    __syncthreads();
    for (int off = 128; off; off >>= 1) {
        if (threadIdx.x < off) s[threadIdx.x] += s[threadIdx.x + off];
        __syncthreads();
    }
    if (threadIdx.x == 0) bsum[blockIdx.x] = s[0];
}

// serial exclusive scan of block sums (nb ~ 196, trivial)
__global__ void k_scan_bsum(int* __restrict__ bsum, int nb) {
    if (blockIdx.x == 0 && threadIdx.x == 0) {
        int run = 0;
        for (int i = 0; i < nb; ++i) { int v = bsum[i]; bsum[i] = run; run += v; }
    }
}

// per-block Hillis-Steele scan + block offset -> exclusive offsets
__global__ void k_offsets(const int* __restrict__ deg, const int* __restrict__ bsum,
                          int* __restrict__ offs, int n) {
    __shared__ int s[256];
    int t = threadIdx.x;
    int i = blockIdx.x * 256 + t;
    int v = (i < n) ? deg[i] : 0;
    s[t] = v;
    __syncthreads();
    for (int off = 1; off < 256; off <<= 1) {
        int x = (t >= off) ? s[t - off] : 0;
        __syncthreads();
        s[t] += x;
        __syncthreads();
    }
    if (i < n) offs[i] = bsum[blockIdx.x] + s[t] - v;   // exclusive
    if (i == n - 1) offs[n] = bsum[blockIdx.x] + s[t];  // total = E
}

__global__ void k_scatter(const int* __restrict__ src, const int* __restrict__ dst,
                          const int* __restrict__ offs, int* __restrict__ cursor,
                          int* __restrict__ csr, int E) {
    int i = blockIdx.x * blockDim.x + threadIdx.x;
    int stride = gridDim.x * blockDim.x;
    for (; i < E; i += stride) {
        int d = dst[i];
        int p = atomicAdd(&cursor[d], 1);
        csr[offs[d] + p] = src[i];
    }
}

// fold bias + BN into per-column affine: y = sum*cs + cb
__global__ void k_affine(const float* __restrict__ b_l, const float* __restrict__ g,
                         const float* __restrict__ be, const float* __restrict__ rm,
                         const float* __restrict__ rv, float* __restrict__ cs,
                         float* __restrict__ cb, int n) {
    int t = blockIdx.x * blockDim.x + threadIdx.x;
    if (t < n) {
        float s = g[t] * rsqrtf(rv[t] + 1e-5f);
        cs[t] = s;
        cb[t] = (b_l[t] - rm[t]) * s + be[t];
    }
}

__global__ void k_affine_pred(const float* __restrict__ pb, float* __restrict__ cs,
                              float* __restrict__ cb, int n) {
    int t = blockIdx.x * blockDim.x + threadIdx.x;
    if (t < n) { cs[t] = 1.0f; cb[t] = pb[t]; }
}

// ---------------- aggregation: mean over CSR neighbors ----------------
// one block per node, blockDim = F/2, each thread owns 2 features (packed u32)
__global__ void k_aggregate(const f16* __restrict__ h, const int* __restrict__ offs,
                            const int* __restrict__ csr, f16* __restrict__ mean) {
    int node = blockIdx.x;
    int t = threadIdx.x;
    int F2 = blockDim.x;
    int beg = offs[node], end = offs[node + 1];
    float a0 = 0.f, a1 = 0.f;
    const unsigned int* base = (const unsigned int*)h;
    for (int j = beg; j < end; ++j) {
        int nbr = csr[j];
        unsigned int v = base[(size_t)nbr * F2 + t];
        union { unsigned int u; f16 h[2]; } cv; cv.u = v;
        a0 += (float)cv.h[0];
        a1 += (float)cv.h[1];
    }
    float inv = (end > beg) ? 1.0f / (float)(end - beg) : 0.0f;
    union { unsigned int u; f16 h[2]; } ov;
    ov.h[0] = (f16)(a0 * inv);
    ov.h[1] = (f16)(a1 * inv);
    ((unsigned int*)mean)[(size_t)node * F2 + t] = ov.u;
}

// ---------------- fused GEMM: out = relu((A1@W1^T + A2@W2^T)*cs + cb) ----------------
// A: [M][K] f16 row-major. W: [FO][K] f16 row-major. out: [M][FO] f16.
// block = (FO/64) waves; wave w covers cols [64w,64w+64); block covers 64 rows.
__global__ __launch_bounds__(256) void k_gemm(
    const f16* __restrict__ A1, const f16* __restrict__ A2,
    const f16* __restrict__ W1, const f16* __restrict__ W2,
    const float* __restrict__ cs, const float* __restrict__ cb,
    f16* __restrict__ out, int M, int K, int FO) {
    int lane = threadIdx.x & 63;
    int wave = threadIdx.x >> 6;
    int m0 = blockIdx.x * 64;
    int n0 = wave * 64;
    int lrow = lane & 15;
    int kof = (lane >> 4) * 8;

    f32x4 acc[4][4] = {};

    const f16* As[2] = {A1, A2};
    const f16* Ws[2] = {W1, W2};
    for (int ph = 0; ph < 2; ++ph) {
        const f16* A = As[ph];
        const f16* W = Ws[ph];
        if (!A) break;
        for (int k0 = 0; k0 < K; k0 += 32) {
            f16x8 a[4], b[4];
#pragma unroll
            for (int mi = 0; mi < 4; ++mi) {
                int row = m0 + mi * 16 + lrow;
                if (row > M - 1) row = M - 1;
                a[mi] = *reinterpret_cast<const f16x8*>(&A[(size_t)row * K + k0 + kof]);
            }
#pragma unroll
            for (int ni = 0; ni < 4; ++ni) {
                int col = n0 + ni * 16 + lrow;
                b[ni] = *reinterpret_cast<const f16x8*>(&W[(size_t)col * K + k0 + kof]);
            }
#pragma unroll
            for (int mi = 0; mi < 4; ++mi)
#pragma unroll
                for (int ni = 0; ni < 4; ++ni)
                    acc[mi][ni] = __builtin_amdgcn_mfma_f32_16x16x32_f16(a[mi], b[ni], acc[mi][ni], 0, 0, 0);
        }
    }

    int rquad = (lane >> 4) * 4;
#pragma unroll
    for (int mi = 0; mi < 4; ++mi) {
#pragma unroll
        for (int ni = 0; ni < 4; ++ni) {
            int col = n0 + ni * 16 + (lane & 15);
            float s = cs[col], c = cb[col];
#pragma unroll
            for (int r = 0; r < 4; ++r) {
                int row = m0 + mi * 16 + rquad + r;
                if (row < M) {
                    float v = acc[mi][ni][r] * s + c;
                    v = fmaxf(v, 0.f);
                    out[(size_t)row * FO + col] = (f16)v;
                }
            }
        }
    }
}

// ---------------- final: out[n] = sigmoid(dot(p2[n,:128], w3) + b3) ----------------
__global__ void k_final(const f16* __restrict__ p2, const f16* __restrict__ w3,
                        const float* __restrict__ pb3, float* __restrict__ out, int M) {
    int gw = (int)((blockIdx.x * (size_t)blockDim.x + threadIdx.x) >> 6);
    int lane = threadIdx.x & 63;
    if (gw >= M) return;
    const unsigned int* row = (const unsigned int*)(p2 + (size_t)gw * 128);
    unsigned int v = row[lane];
    unsigned int wv = ((const unsigned int*)w3)[lane];
    union { unsigned int u; f16 h[2]; } cv, cw;
    cv.u = v; cw.u = wv;
    float s = (float)cv.h[0] * (float)cw.h[0] + (float)cv.h[1] * (float)cw.h[1];
    for (int off = 32; off; off >>= 1) s += __shfl_down(s, off);
    if (lane == 0) out[gw] = 1.0f / (1.0f + expf(-(s + pb3[0])));
}

// ---------------- launch ----------------

extern "C" void kernel_launch(void* const* d_in, const int* in_sizes, int n_in,
                              void* d_out, int out_size, void* d_ws, size_t ws_size,
                              hipStream_t stream) {
    const float* x = (const float*)d_in[0];
    const int* ei = (const int*)d_in[1];
    const int* src = ei;
    const int* dst = ei + NEDGES;
    const float* w_l[3] = {(const float*)d_in[2], (const float*)d_in[9], (const float*)d_in[16]};
    const float* b_l[3] = {(const float*)d_in[3], (const float*)d_in[10], (const float*)d_in[17]};
    const float* w_r[3] = {(const float*)d_in[4], (const float*)d_in[11], (const float*)d_in[18]};
    const float* g[3]  = {(const float*)d_in[5], (const float*)d_in[12], (const float*)d_in[19]};
    const float* be[3] = {(const float*)d_in[6], (const float*)d_in[13], (const float*)d_in[20]};
    const float* rm[3] = {(const float*)d_in[7], (const float*)d_in[14], (const float*)d_in[21]};
    const float* rv[3] = {(const float*)d_in[8], (const float*)d_in[15], (const float*)d_in[22]};
    const float* pw1 = (const float*)d_in[23]; const float* pb1 = (const float*)d_in[24];
    const float* pw2 = (const float*)d_in[25]; const float* pb2 = (const float*)d_in[26];
    const float* pw3 = (const float*)d_in[27]; const float* pb3 = (const float*)d_in[28];

    char* wsb = (char*)d_ws;
    size_t o = 0;
    auto alloc = [&](size_t b) { size_t r = o; o = (o + b + 255) & ~(size_t)255; return r; };

    int* deg    = (int*)(wsb + alloc(NNODES * 4));
    int* cursor = (int*)(wsb + alloc(NNODES * 4));
    int* offs   = (int*)(wsb + alloc((NNODES + 1) * 4));
    int* bsum   = (int*)(wsb + alloc(256 * 4));
    int* csr    = (int*)(wsb + alloc(NEDGES * 4));
    f16* h0   = (f16*)(wsb + alloc((size_t)NNODES * 128 * 2));
    f16* hA   = (f16*)(wsb + alloc((size_t)NNODES * 256 * 2));
    f16* hB   = (f16*)(wsb + alloc((size_t)NNODES * 256 * 2));
    f16* mean = (f16*)(wsb + alloc((size_t)NNODES * 256 * 2));
    f16* wl0f = (f16*)(wsb + alloc(256 * 128 * 2));
    f16* wr0f = (f16*)(wsb + alloc(256 * 128 * 2));
    f16* wl1f = (f16*)(wsb + alloc(256 * 256 * 2));
    f16* wr1f = (f16*)(wsb + alloc(256 * 256 * 2));
    f16* wl2f = (f16*)(wsb + alloc(256 * 256 * 2));
    f16* wr2f = (f16*)(wsb + alloc(256 * 256 * 2));
    f16* pw1f = (f16*)(wsb + alloc(256 * 256 * 2));
    f16* pw2f = (f16*)(wsb + alloc(128 * 256 * 2));
    f16* pw3f = (f16*)(wsb + alloc(128 * 2));
    float* csv[5]; float* cbv[5];
    for (int i = 0; i < 5; ++i) {
        csv[i] = (float*)(wsb + alloc(256 * 4));
        cbv[i] = (float*)(wsb + alloc(256 * 4));
    }
    f16* p2 = h0;  // reuse (x-f16 dead by then)

    // --- CSR build ---
    hipMemsetAsync(deg, 0, NNODES * 4, stream);
    hipMemsetAsync(cursor, 0, NNODES * 4, stream);
    k_deg<<<3125, 256, 0, stream>>>(dst, deg, NEDGES);
    int nb = (NNODES + 255) / 256;  // 196
    k_bsum<<<nb, 256, 0, stream>>>(deg, bsum, NNODES);
    k_scan_bsum<<<1, 64, 0, stream>>>(bsum, nb);
    k_offsets<<<nb, 256, 0, stream>>>(deg, bsum, offs, NNODES);
    k_scatter<<<3125, 256, 0, stream>>>(src, dst, offs, cursor, csr, NEDGES);

    // --- weight + input conversion ---
    k_cvt<<<2048, 256, 0, stream>>>(x, h0, NNODES * 128);
    k_cvt<<<128, 256, 0, stream>>>(w_l[0], wl0f, 256 * 128);
    k_cvt<<<128, 256, 0, stream>>>(w_r[0], wr0f, 256 * 128);
    k_cvt<<<256, 256, 0, stream>>>(w_l[1], wl1f, 256 * 256);
    k_cvt<<<256, 256, 0, stream>>>(w_r[1], wr1f, 256 * 256);
    k_cvt<<<256, 256, 0, stream>>>(w_l[2], wl2f, 256 * 256);
    k_cvt<<<256, 256, 0, stream>>>(w_r[2], wr2f, 256 * 256);
    k_cvt<<<256, 256, 0, stream>>>(pw1, pw1f, 256 * 256);
    k_cvt<<<128, 256, 0, stream>>>(pw2, pw2f, 128 * 256);
    k_cvt<<<1, 128, 0, stream>>>(pw3, pw3f, 128);

    for (int i = 0; i < 3; ++i)
        k_affine<<<1, 256, 0, stream>>>(b_l[i], g[i], be[i], rm[i], rv[i], csv[i], cbv[i], 256);
    k_affine_pred<<<1, 256, 0, stream>>>(pb1, csv[3], cbv[3], 256);
    k_affine_pred<<<1, 128, 0, stream>>>(pb2, csv[4], cbv[4], 128);

    int gm = (NNODES + 63) / 64;  // 782

    // --- layer 0: F_in=128 ---
    k_aggregate<<<NNODES, 64, 0, stream>>>(h0, offs, csr, mean);
    k_gemm<<<gm, 256, 0, stream>>>(mean, h0, wl0f, wr0f, csv[0], cbv[0], hA, NNODES, 128, 256);
    // --- layer 1 ---
    k_aggregate<<<NNODES, 128, 0, stream>>>(hA, offs, csr, mean);
    k_gemm<<<gm, 256, 0, stream>>>(mean, hA, wl1f, wr1f, csv[1], cbv[1], hB, NNODES, 256, 256);
    // --- layer 2 ---
    k_aggregate<<<NNODES, 128, 0, stream>>>(hB, offs, csr, mean);
    k_gemm<<<gm, 256, 0, stream>>>(mean, hB, wl2f, wr2f, csv[2], cbv[2], hA, NNODES, 256, 256);
    // --- predictor ---
    k_gemm<<<gm, 256, 0, stream>>>(hA, nullptr, pw1f, nullptr, csv[3], cbv[3], hB, NNODES, 256, 256);
    k_gemm<<<gm, 128, 0, stream>>>(hB, nullptr, pw2f, nullptr, csv[4], cbv[4], p2, NNODES, 256, 128);
    k_final<<<(NNODES + 3) / 4, 256, 0, stream>>>(p2, pw3f, pb3, (float*)d_out, NNODES);
}

// Round 2
// 449.186 us; speedup vs baseline: 1.4015x; 1.4015x over previous
//
#include <hip/hip_runtime.h>
#include <hip/hip_fp16.h>

#define NNODES 50000
#define NEDGES 800000

typedef _Float16 f16;
typedef f16 f16x8 __attribute__((ext_vector_type(8)));
typedef f16 f16x4 __attribute__((ext_vector_type(4)));
typedef float f32x4 __attribute__((ext_vector_type(4)));

#define GLOAD_LDS16(g, l) __builtin_amdgcn_global_load_lds( \
    (const __attribute__((address_space(1))) void*)(g), \
    (__attribute__((address_space(3))) void*)(l), 16, 0, 0)

// ---------------- CSR build ----------------

__global__ void k_deg(const int* __restrict__ dst, int* __restrict__ deg, int E) {
    int i = blockIdx.x * blockDim.x + threadIdx.x;
    int stride = gridDim.x * blockDim.x;
    for (; i < E; i += stride) atomicAdd(&deg[dst[i]], 1);
}

__global__ void k_bsum(const int* __restrict__ deg, int* __restrict__ bsum, int n) {
    __shared__ int s[256];
    int i = blockIdx.x * 256 + threadIdx.x;
    s[threadIdx.x] = (i < n) ? deg[i] : 0;
    __syncthreads();
    for (int off = 128; off; off >>= 1) {
        if (threadIdx.x < off) s[threadIdx.x] += s[threadIdx.x + off];
        __syncthreads();
    }
    if (threadIdx.x == 0) bsum[blockIdx.x] = s[0];
}

__global__ void k_scan_bsum(int* __restrict__ bsum, int nb) {
    if (blockIdx.x == 0 && threadIdx.x == 0) {
        int run = 0;
        for (int i = 0; i < nb; ++i) { int v = bsum[i]; bsum[i] = run; run += v; }
    }
}

__global__ void k_offsets(const int* __restrict__ deg, const int* __restrict__ bsum,
                          int* __restrict__ offs, int n) {
    __shared__ int s[256];
    int t = threadIdx.x;
    int i = blockIdx.x * 256 + t;
    int v = (i < n) ? deg[i] : 0;
    s[t] = v;
    __syncthreads();
    for (int off = 1; off < 256; off <<= 1) {
        int x = (t >= off) ? s[t - off] : 0;
        __syncthreads();
        s[t] += x;
        __syncthreads();
    }
    if (i < n) offs[i] = bsum[blockIdx.x] + s[t] - v;
    if (i == n - 1) offs[n] = bsum[blockIdx.x] + s[t];
}

__global__ void k_scatter(const int* __restrict__ src, const int* __restrict__ dst,
                          const int* __restrict__ offs, int* __restrict__ cursor,
                          int* __restrict__ csr, int E) {
    int i = blockIdx.x * blockDim.x + threadIdx.x;
    int stride = gridDim.x * blockDim.x;
    for (; i < E; i += stride) {
        int d = dst[i];
        int p = atomicAdd(&cursor[d], 1);
        csr[offs[d] + p] = src[i];
    }
}

// ---------------- fused weight conversion (one launch) ----------------

#define NSEG 11
struct CvtSeg { const float* s; f16* d; int n4; };  // n4 = n/4
struct CvtArgs { CvtSeg seg[NSEG]; };

__global__ void k_prep(CvtArgs a) {
    int gid = blockIdx.x * blockDim.x + threadIdx.x;
    int gstride = gridDim.x * blockDim.x;
    for (int s = 0; s < NSEG; ++s) {
        const float4* sp = (const float4*)a.seg[s].s;
        f16x4* dp = (f16x4*)a.seg[s].d;
        int n4 = a.seg[s].n4;
        for (int i = gid; i < n4; i += gstride) {
            float4 v = sp[i];
            f16x4 o;
            o[0] = (f16)v.x; o[1] = (f16)v.y; o[2] = (f16)v.z; o[3] = (f16)v.w;
            dp[i] = o;
        }
    }
}

// ---------------- affine folds (bias+BN -> y = sum*cs + cb), one launch ----------------

struct AffSeg { const float *b, *g, *be, *rm, *rv; float *cs, *cb; int n; int isbn; };
struct AffArgs { AffSeg s[5]; };

__global__ void k_affine_all(AffArgs a) {
    AffSeg sg = a.s[blockIdx.x];
    int t = threadIdx.x;
    if (t < sg.n) {
        if (sg.isbn) {
            float sc = sg.g[t] * rsqrtf(sg.rv[t] + 1e-5f);
            sg.cs[t] = sc;
            sg.cb[t] = (sg.b[t] - sg.rm[t]) * sc + sg.be[t];
        } else {
            sg.cs[t] = 1.0f;
            sg.cb[t] = sg.b[t];
        }
    }
}

// ---------------- aggregation: mean over CSR neighbors ----------------
// wave per node; LPN = F/8 lanes cover one neighbor row with f16x8 loads;
// GPN = 64/LPN neighbors concurrent per wave; 4-deep manual unroll.
template <int F>
__global__ __launch_bounds__(256) void k_aggregate(
    const f16* __restrict__ h, const int* __restrict__ offs,
    const int* __restrict__ csr, f16* __restrict__ mean) {
    constexpr int LPN = F / 8;
    constexpr int GPN = 64 / LPN;
    int wave = threadIdx.x >> 6;
    int node = blockIdx.x * 4 + wave;
    if (node >= NNODES) return;
    int lane = threadIdx.x & 63;
    int g = lane / LPN;
    int t = lane % LPN;
    int beg = offs[node], end = offs[node + 1];

    float acc[8] = {0.f, 0.f, 0.f, 0.f, 0.f, 0.f, 0.f, 0.f};
    const f16x8* hb = (const f16x8*)h;

    int j = beg + g;
    for (; j + 3 * GPN < end; j += 4 * GPN) {
        int n0 = csr[j], n1 = csr[j + GPN], n2 = csr[j + 2 * GPN], n3 = csr[j + 3 * GPN];
        f16x8 v0 = hb[(size_t)n0 * LPN + t];
        f16x8 v1 = hb[(size_t)n1 * LPN + t];
        f16x8 v2 = hb[(size_t)n2 * LPN + t];
        f16x8 v3 = hb[(size_t)n3 * LPN + t];
#pragma unroll
        for (int e = 0; e < 8; ++e)
            acc[e] += (float)v0[e] + (float)v1[e] + (float)v2[e] + (float)v3[e];
    }
    for (; j < end; j += GPN) {
        int n0 = csr[j];
        f16x8 v0 = hb[(size_t)n0 * LPN + t];
#pragma unroll
        for (int e = 0; e < 8; ++e) acc[e] += (float)v0[e];
    }

#pragma unroll
    for (int off = LPN; off < 64; off <<= 1)
#pragma unroll
        for (int e = 0; e < 8; ++e) acc[e] += __shfl_xor(acc[e], off);

    if (g == 0) {
        float inv = (end > beg) ? 1.0f / (float)(end - beg) : 0.0f;
        f16x8 o;
#pragma unroll
        for (int e = 0; e < 8; ++e) o[e] = (f16)(acc[e] * inv);
        ((f16x8*)mean)[(size_t)node * LPN + t] = o;
    }
}

// ---------------- fused GEMM: out = relu((A1@W1^T + A2@W2^T)*cs + cb) ----------------
// A: [M][K] f16. W: [FO][K] f16. out: [M][FO] f16.
// Block: FO/64 waves; 64-row tile; A staged via global_load_lds into
// double-buffered, XOR-swizzled LDS (BK=64); B frags read direct (L2-hot).
__global__ __launch_bounds__(256) void k_gemm(
    const f16* __restrict__ A1, const f16* __restrict__ A2,
    const f16* __restrict__ W1, const f16* __restrict__ W2,
    const float* __restrict__ cs, const float* __restrict__ cb,
    f16* __restrict__ out, int M, int K, int FO) {
    __shared__ f16 smem[2][64 * 64];
    int tid = threadIdx.x;
    int nthr = blockDim.x;
    int lane = tid & 63;
    int wave = tid >> 6;
    int m0 = blockIdx.x * 64;
    int n0 = wave * 64;
    int lrow = lane & 15;
    int kof8 = (lane >> 4) * 8;           // element offset within 32-wide k-step
    int KC1 = K >> 6;                     // 64-chunks per phase
    int NC = A2 ? (KC1 * 2) : KC1;

    auto stage = [&](int buf, int c) {
        int ph = (c >= KC1) ? 1 : 0;
        const char* Ab = (const char*)(ph ? A2 : A1);
        char* Lb = (char*)&smem[buf][0];
        int kloc2 = (c - ph * KC1) << 7;  // byte offset within phase row
        for (int u = tid; u < 512; u += nthr) {
            int row = u >> 3;
            int kb = (u & 7) * 16;        // swizzled LDS slot -> inverse-swizzle the source
            int grow = m0 + row; if (grow > M - 1) grow = M - 1;
            const char* src = Ab + (size_t)grow * (K * 2) + kloc2 + (kb ^ ((row & 7) << 4));
            GLOAD_LDS16(src, Lb + u * 16);
        }
    };

    f32x4 acc[4][4] = {};

    stage(0, 0);
    __syncthreads();

    for (int c = 0; c < NC; ++c) {
        int cur = c & 1;
        int ph = (c >= KC1) ? 1 : 0;
        const f16* W = ph ? W2 : W1;
        int kloc = (c - ph * KC1) << 6;
        const char* Lb = (const char*)&smem[cur][0];

        f16x8 a[2][4], b[2][4];
#pragma unroll
        for (int kk = 0; kk < 2; ++kk) {
#pragma unroll
            for (int mi = 0; mi < 4; ++mi) {
                int r = mi * 16 + lrow;
                int kb = kof8 * 2 + kk * 64;
                a[kk][mi] = *(const f16x8*)(Lb + r * 128 + (kb ^ ((r & 7) << 4)));
            }
#pragma unroll
            for (int ni = 0; ni < 4; ++ni) {
                int col = n0 + ni * 16 + lrow;
                b[kk][ni] = *(const f16x8*)(&W[(size_t)col * K + kloc + kk * 32 + kof8]);
            }
        }

        if (c + 1 < NC) stage(cur ^ 1, c + 1);  // issue AFTER b-loads so their wait is vmcnt(2)

#pragma unroll
        for (int kk = 0; kk < 2; ++kk)
#pragma unroll
            for (int mi = 0; mi < 4; ++mi)
#pragma unroll
                for (int ni = 0; ni < 4; ++ni)
                    acc[mi][ni] = __builtin_amdgcn_mfma_f32_16x16x32_f16(a[kk][mi], b[kk][ni], acc[mi][ni], 0, 0, 0);

        __syncthreads();
    }

    int rquad = (lane >> 4) * 4;
#pragma unroll
    for (int mi = 0; mi < 4; ++mi) {
#pragma unroll
        for (int ni = 0; ni < 4; ++ni) {
            int col = n0 + ni * 16 + (lane & 15);
            float s = cs[col], cc = cb[col];
#pragma unroll
            for (int r = 0; r < 4; ++r) {
                int row = m0 + mi * 16 + rquad + r;
                if (row < M) {
                    float v = acc[mi][ni][r] * s + cc;
                    v = fmaxf(v, 0.f);
                    out[(size_t)row * FO + col] = (f16)v;
                }
            }
        }
    }
}

// ---------------- final: out[n] = sigmoid(dot(p2[n,:128], w3) + b3) ----------------
__global__ void k_final(const f16* __restrict__ p2, const f16* __restrict__ w3,
                        const float* __restrict__ pb3, float* __restrict__ out, int M) {
    int gw = (int)((blockIdx.x * (size_t)blockDim.x + threadIdx.x) >> 6);
    int lane = threadIdx.x & 63;
    if (gw >= M) return;
    const unsigned int* row = (const unsigned int*)(p2 + (size_t)gw * 128);
    unsigned int v = row[lane];
    unsigned int wv = ((const unsigned int*)w3)[lane];
    union { unsigned int u; f16 h[2]; } cv, cw;
    cv.u = v; cw.u = wv;
    float s = (float)cv.h[0] * (float)cw.h[0] + (float)cv.h[1] * (float)cw.h[1];
    for (int off = 32; off; off >>= 1) s += __shfl_down(s, off);
    if (lane == 0) out[gw] = 1.0f / (1.0f + expf(-(s + pb3[0])));
}

// ---------------- launch ----------------

extern "C" void kernel_launch(void* const* d_in, const int* in_sizes, int n_in,
                              void* d_out, int out_size, void* d_ws, size_t ws_size,
                              hipStream_t stream) {
    const float* x = (const float*)d_in[0];
    const int* ei = (const int*)d_in[1];
    const int* src = ei;
    const int* dst = ei + NEDGES;
    const float* w_l[3] = {(const float*)d_in[2], (const float*)d_in[9], (const float*)d_in[16]};
    const float* b_l[3] = {(const float*)d_in[3], (const float*)d_in[10], (const float*)d_in[17]};
    const float* w_r[3] = {(const float*)d_in[4], (const float*)d_in[11], (const float*)d_in[18]};
    const float* g[3]  = {(const float*)d_in[5], (const float*)d_in[12], (const float*)d_in[19]};
    const float* be[3] = {(const float*)d_in[6], (const float*)d_in[13], (const float*)d_in[20]};
    const float* rm[3] = {(const float*)d_in[7], (const float*)d_in[14], (const float*)d_in[21]};
    const float* rv[3] = {(const float*)d_in[8], (const float*)d_in[15], (const float*)d_in[22]};
    const float* pw1 = (const float*)d_in[23]; const float* pb1 = (const float*)d_in[24];
    const float* pw2 = (const float*)d_in[25]; const float* pb2 = (const float*)d_in[26];
    const float* pw3 = (const float*)d_in[27]; const float* pb3 = (const float*)d_in[28];

    char* wsb = (char*)d_ws;
    size_t o = 0;
    auto alloc = [&](size_t b) { size_t r = o; o = (o + b + 255) & ~(size_t)255; return r; };

    int* deg    = (int*)(wsb + alloc(NNODES * 4));
    int* cursor = (int*)(wsb + alloc(NNODES * 4));
    int* offs   = (int*)(wsb + alloc((NNODES + 1) * 4));
    int* bsum   = (int*)(wsb + alloc(256 * 4));
    int* csr    = (int*)(wsb + alloc(NEDGES * 4));
    f16* h0   = (f16*)(wsb + alloc((size_t)NNODES * 128 * 2));
    f16* hA   = (f16*)(wsb + alloc((size_t)NNODES * 256 * 2));
    f16* hB   = (f16*)(wsb + alloc((size_t)NNODES * 256 * 2));
    f16* mean = (f16*)(wsb + alloc((size_t)NNODES * 256 * 2));
    f16* wl0f = (f16*)(wsb + alloc(256 * 128 * 2));
    f16* wr0f = (f16*)(wsb + alloc(256 * 128 * 2));
    f16* wl1f = (f16*)(wsb + alloc(256 * 256 * 2));
    f16* wr1f = (f16*)(wsb + alloc(256 * 256 * 2));
    f16* wl2f = (f16*)(wsb + alloc(256 * 256 * 2));
    f16* wr2f = (f16*)(wsb + alloc(256 * 256 * 2));
    f16* pw1f = (f16*)(wsb + alloc(256 * 256 * 2));
    f16* pw2f = (f16*)(wsb + alloc(128 * 256 * 2));
    f16* pw3f = (f16*)(wsb + alloc(128 * 2));
    float* csv[5]; float* cbv[5];
    for (int i = 0; i < 5; ++i) {
        csv[i] = (float*)(wsb + alloc(256 * 4));
        cbv[i] = (float*)(wsb + alloc(256 * 4));
    }
    f16* p2 = h0;  // reuse (x-f16 dead by then)

    // --- CSR build ---
    hipMemsetAsync(deg, 0, NNODES * 4, stream);
    hipMemsetAsync(cursor, 0, NNODES * 4, stream);
    k_deg<<<3125, 256, 0, stream>>>(dst, deg, NEDGES);
    int nb = (NNODES + 255) / 256;  // 196
    k_bsum<<<nb, 256, 0, stream>>>(deg, bsum, NNODES);
    k_scan_bsum<<<1, 64, 0, stream>>>(bsum, nb);
    k_offsets<<<nb, 256, 0, stream>>>(deg, bsum, offs, NNODES);
    k_scatter<<<3125, 256, 0, stream>>>(src, dst, offs, cursor, csr, NEDGES);

    // --- all float->f16 conversions in one launch ---
    CvtArgs ca;
    ca.seg[0]  = {x,       h0,   NNODES * 128 / 4};
    ca.seg[1]  = {w_l[0],  wl0f, 256 * 128 / 4};
    ca.seg[2]  = {w_r[0],  wr0f, 256 * 128 / 4};
    ca.seg[3]  = {w_l[1],  wl1f, 256 * 256 / 4};
    ca.seg[4]  = {w_r[1],  wr1f, 256 * 256 / 4};
    ca.seg[5]  = {w_l[2],  wl2f, 256 * 256 / 4};
    ca.seg[6]  = {w_r[2],  wr2f, 256 * 256 / 4};
    ca.seg[7]  = {pw1,     pw1f, 256 * 256 / 4};
    ca.seg[8]  = {pw2,     pw2f, 128 * 256 / 4};
    ca.seg[9]  = {pw3,     pw3f, 128 / 4};
    ca.seg[10] = {pw3,     pw3f, 0};  // pad
    k_prep<<<2048, 256, 0, stream>>>(ca);

    AffArgs aa;
    for (int i = 0; i < 3; ++i)
        aa.s[i] = {b_l[i], g[i], be[i], rm[i], rv[i], csv[i], cbv[i], 256, 1};
    aa.s[3] = {pb1, nullptr, nullptr, nullptr, nullptr, csv[3], cbv[3], 256, 0};
    aa.s[4] = {pb2, nullptr, nullptr, nullptr, nullptr, csv[4], cbv[4], 128, 0};
    k_affine_all<<<5, 256, 0, stream>>>(aa);

    int gm = (NNODES + 63) / 64;    // 782
    int ga = (NNODES + 3) / 4;      // 12500

    // --- layer 0 (F_in=128) ---
    k_aggregate<128><<<ga, 256, 0, stream>>>(h0, offs, csr, mean);
    k_gemm<<<gm, 256, 0, stream>>>(mean, h0, wl0f, wr0f, csv[0], cbv[0], hA, NNODES, 128, 256);
    // --- layer 1 ---
    k_aggregate<256><<<ga, 256, 0, stream>>>(hA, offs, csr, mean);
    k_gemm<<<gm, 256, 0, stream>>>(mean, hA, wl1f, wr1f, csv[1], cbv[1], hB, NNODES, 256, 256);
    // --- layer 2 ---
    k_aggregate<256><<<ga, 256, 0, stream>>>(hB, offs, csr, mean);
    k_gemm<<<gm, 256, 0, stream>>>(mean, hB, wl2f, wr2f, csv[2], cbv[2], hA, NNODES, 256, 256);
    // --- predictor ---
    k_gemm<<<gm, 256, 0, stream>>>(hA, nullptr, pw1f, nullptr, csv[3], cbv[3], hB, NNODES, 256, 256);
    k_gemm<<<gm, 128, 0, stream>>>(hB, nullptr, pw2f, nullptr, csv[4], cbv[4], p2, NNODES, 256, 128);
    k_final<<<ga, 256, 0, stream>>>(p2, pw3f, pb3, (float*)d_out, NNODES);
}

// Round 3
// 446.569 us; speedup vs baseline: 1.4097x; 1.0059x over previous
//
#include <hip/hip_runtime.h>
#include <hip/hip_fp16.h>

#define NNODES 50000
#define NEDGES 800000

typedef _Float16 f16;
typedef f16 f16x8 __attribute__((ext_vector_type(8)));
typedef f16 f16x4 __attribute__((ext_vector_type(4)));
typedef float f32x4 __attribute__((ext_vector_type(4)));

#define GLOAD_LDS16(g, l) __builtin_amdgcn_global_load_lds( \
    (const __attribute__((address_space(1))) void*)(g), \
    (__attribute__((address_space(3))) void*)(l), 16, 0, 0)

// ---------------- CSR build (degree-padded to multiples of 8) ----------------

__global__ void k_deg(const int* __restrict__ dst, int* __restrict__ deg, int E) {
    int i = blockIdx.x * blockDim.x + threadIdx.x;
    int stride = gridDim.x * blockDim.x;
    for (; i < E; i += stride) atomicAdd(&deg[dst[i]], 1);
}

__global__ void k_bsum(const int* __restrict__ deg, int* __restrict__ bsum, int n) {
    __shared__ int s[256];
    int i = blockIdx.x * 256 + threadIdx.x;
    s[threadIdx.x] = (i < n) ? ((deg[i] + 7) & ~7) : 0;   // padded degree
    __syncthreads();
    for (int off = 128; off; off >>= 1) {
        if (threadIdx.x < off) s[threadIdx.x] += s[threadIdx.x + off];
        __syncthreads();
    }
    if (threadIdx.x == 0) bsum[blockIdx.x] = s[0];
}

__global__ void k_scan_bsum(int* __restrict__ bsum, int nb) {
    if (blockIdx.x == 0 && threadIdx.x == 0) {
        int run = 0;
        for (int i = 0; i < nb; ++i) { int v = bsum[i]; bsum[i] = run; run += v; }
    }
}

__global__ void k_offsets(const int* __restrict__ deg, const int* __restrict__ bsum,
                          int* __restrict__ offs, int n) {
    __shared__ int s[256];
    int t = threadIdx.x;
    int i = blockIdx.x * 256 + t;
    int v = (i < n) ? ((deg[i] + 7) & ~7) : 0;            // padded degree
    s[t] = v;
    __syncthreads();
    for (int off = 1; off < 256; off <<= 1) {
        int x = (t >= off) ? s[t - off] : 0;
        __syncthreads();
        s[t] += x;
        __syncthreads();
    }
    if (i < n) offs[i] = bsum[blockIdx.x] + s[t] - v;
    if (i == n - 1) offs[n] = bsum[blockIdx.x] + s[t];
}

__global__ void k_scatter(const int* __restrict__ src, const int* __restrict__ dst,
                          const int* __restrict__ offs, int* __restrict__ cursor,
                          int* __restrict__ csr, int E) {
    int i = blockIdx.x * blockDim.x + threadIdx.x;
    int stride = gridDim.x * blockDim.x;
    for (; i < E; i += stride) {
        int d = dst[i];
        int p = atomicAdd(&cursor[d], 1);
        csr[offs[d] + p] = src[i];
    }
}

// fill pad slots with index NNODES (the all-zero feature row)
__global__ void k_pad(const int* __restrict__ deg, const int* __restrict__ offs,
                      int* __restrict__ csr, int n) {
    int i = blockIdx.x * blockDim.x + threadIdx.x;
    if (i >= n) return;
    int d = deg[i], pd = (d + 7) & ~7;
    int base = offs[i];
    for (int p = d; p < pd; ++p) csr[base + p] = NNODES;
}

// ---------------- fused weight conversion (one launch) ----------------

#define NSEG 9
struct CvtSeg { const float* s; f16* d; int n4; };
struct CvtArgs { CvtSeg seg[NSEG]; };

__global__ void k_prep(CvtArgs a) {
    int gid = blockIdx.x * blockDim.x + threadIdx.x;
    int gstride = gridDim.x * blockDim.x;
    for (int s = 0; s < NSEG; ++s) {
        const float4* sp = (const float4*)a.seg[s].s;
        f16x4* dp = (f16x4*)a.seg[s].d;
        int n4 = a.seg[s].n4;
        for (int i = gid; i < n4; i += gstride) {
            float4 v = sp[i];
            f16x4 o;
            o[0] = (f16)v.x; o[1] = (f16)v.y; o[2] = (f16)v.z; o[3] = (f16)v.w;
            dp[i] = o;
        }
    }
}

// ---------------- affine folds ----------------

struct AffSeg { const float *b, *g, *be, *rm, *rv; float *cs, *cb; int n; int isbn; };
struct AffArgs { AffSeg s[5]; };

__global__ void k_affine_all(AffArgs a) {
    AffSeg sg = a.s[blockIdx.x];
    int t = threadIdx.x;
    if (t < sg.n) {
        if (sg.isbn) {
            float sc = sg.g[t] * rsqrtf(sg.rv[t] + 1e-5f);
            sg.cs[t] = sc;
            sg.cb[t] = (sg.b[t] - sg.rm[t]) * sc + sg.be[t];
        } else {
            sg.cs[t] = 1.0f;
            sg.cb[t] = sg.b[t];
        }
    }
}

// ---------------- aggregation: mean over padded CSR ----------------
// LPN = F/8 lanes own one node's row (8 features/lane, exclusive -> no reduce).
// 64/LPN nodes per wave; uniform 8-deep gather loop (padding guarantees %8==0).
template <int F>
__global__ __launch_bounds__(256) void k_aggregate(
    const f16* __restrict__ h, const int* __restrict__ poffs,
    const int* __restrict__ deg, const int* __restrict__ csr,
    f16* __restrict__ mean) {
    constexpr int LPN = F / 8;
    constexpr int NPW = 64 / LPN;
    int tid = threadIdx.x;
    int wave = tid >> 6, lane = tid & 63;
    int node = blockIdx.x * (4 * NPW) + wave * NPW + lane / LPN;
    int t = lane % LPN;
    int beg = poffs[node], end = poffs[node + 1];

    float acc[8] = {0.f, 0.f, 0.f, 0.f, 0.f, 0.f, 0.f, 0.f};
    const f16x8* hb = (const f16x8*)h;

    for (int j = beg; j < end; j += 8) {
        int n[8];
        f16x8 v[8];
#pragma unroll
        for (int u = 0; u < 8; ++u) n[u] = csr[j + u];
#pragma unroll
        for (int u = 0; u < 8; ++u) v[u] = hb[(size_t)n[u] * LPN + t];
#pragma unroll
        for (int u = 0; u < 8; ++u)
#pragma unroll
            for (int e = 0; e < 8; ++e) acc[e] += (float)v[u][e];
    }

    int d = deg[node];
    float inv = (d > 0) ? 1.0f / (float)d : 0.0f;
    f16x8 o;
#pragma unroll
    for (int e = 0; e < 8; ++e) o[e] = (f16)(acc[e] * inv);
    ((f16x8*)mean)[(size_t)node * LPN + t] = o;
}

// ---------------- fused GEMM: out = relu((A1@W1^T + A2@W2^T)*cs + cb) ----------------
// A staged via global_load_lds (XOR-swizzled, double-buffered, BK=64);
// B fragments register-double-buffered (prefetched one chunk ahead).
// FUSE: epilogue computes sigmoid(relu(row)@w3 + b3) directly (predictor tail).
template <bool FUSE>
__global__ __launch_bounds__(256) void k_gemm(
    const f16* __restrict__ A1, const f16* __restrict__ A2,
    const f16* __restrict__ W1, const f16* __restrict__ W2,
    const float* __restrict__ cs, const float* __restrict__ cb,
    f16* __restrict__ out, const float* __restrict__ w3,
    const float* __restrict__ pb3, float* __restrict__ outF,
    int M, int K, int FO) {
    __shared__ f16 smem[2][64 * 64];
    __shared__ float smF[2][64];
    int tid = threadIdx.x;
    int nthr = blockDim.x;
    int lane = tid & 63;
    int wave = tid >> 6;
    int m0 = blockIdx.x * 64;
    int n0 = wave * 64;
    int lrow = lane & 15;
    int kof8 = (lane >> 4) * 8;
    int KC1 = K >> 6;
    int NC = A2 ? (KC1 * 2) : KC1;   // always even (K in {128,256})

    auto stage = [&](int buf, int c) {
        int ph = (c >= KC1) ? 1 : 0;
        const char* Ab = (const char*)(ph ? A2 : A1);
        char* Lb = (char*)&smem[buf][0];
        int kloc2 = (c - ph * KC1) << 7;
        for (int u = tid; u < 512; u += nthr) {
            int row = u >> 3;
            int kb = (u & 7) * 16;
            int grow = m0 + row; if (grow > M - 1) grow = M - 1;
            const char* src = Ab + (size_t)grow * (K * 2) + kloc2 + (kb ^ ((row & 7) << 4));
            GLOAD_LDS16(src, Lb + u * 16);
        }
    };

    f16x8 bA[2][4], bB[2][4];
    auto loadB = [&](f16x8 (&bb)[2][4], int c) {
        int ph = (c >= KC1) ? 1 : 0;
        const f16* W = ph ? W2 : W1;
        int kloc = (c - ph * KC1) << 6;
#pragma unroll
        for (int kk = 0; kk < 2; ++kk)
#pragma unroll
            for (int ni = 0; ni < 4; ++ni) {
                int col = n0 + ni * 16 + lrow;
                bb[kk][ni] = *(const f16x8*)(&W[(size_t)col * K + kloc + kk * 32 + kof8]);
            }
    };

    f32x4 acc[4][4] = {};
    auto domfma = [&](const f16x8 (&bb)[2][4], int buf) {
        const char* Lb = (const char*)&smem[buf][0];
#pragma unroll
        for (int kk = 0; kk < 2; ++kk) {
            f16x8 a[4];
#pragma unroll
            for (int mi = 0; mi < 4; ++mi) {
                int r = mi * 16 + lrow;
                int kb = kof8 * 2 + kk * 64;
                a[mi] = *(const f16x8*)(Lb + r * 128 + (kb ^ ((r & 7) << 4)));
            }
#pragma unroll
            for (int mi = 0; mi < 4; ++mi)
#pragma unroll
                for (int ni = 0; ni < 4; ++ni)
                    acc[mi][ni] = __builtin_amdgcn_mfma_f32_16x16x32_f16(a[mi], bb[kk][ni], acc[mi][ni], 0, 0, 0);
        }
    };

    stage(0, 0);
    loadB(bA, 0);
    __syncthreads();

    for (int c = 0; c < NC; c += 2) {
        loadB(bB, c + 1);
        stage(1, c + 1);
        domfma(bA, 0);          // bA completed by previous barrier's drain
        __syncthreads();
        if (c + 2 < NC) {
            loadB(bA, c + 2);
            stage(0, c + 2);
        }
        domfma(bB, 1);
        __syncthreads();
    }

    if constexpr (!FUSE) {
        int rquad = (lane >> 4) * 4;
#pragma unroll
        for (int mi = 0; mi < 4; ++mi) {
#pragma unroll
            for (int ni = 0; ni < 4; ++ni) {
                int col = n0 + ni * 16 + (lane & 15);
                float s = cs[col], cc = cb[col];
#pragma unroll
                for (int r = 0; r < 4; ++r) {
                    int row = m0 + mi * 16 + rquad + r;
                    if (row < M) {
                        float v = acc[mi][ni][r] * s + cc;
                        v = fmaxf(v, 0.f);
                        out[(size_t)row * FO + col] = (f16)v;
                    }
                }
            }
        }
    } else {
        // predictor tail: s_row = sum_col relu(acc+cb[col]) * w3[col]; sigmoid(s_row+b3)
        float b3 = pb3[0];
        float rsum[4][4] = {};
#pragma unroll
        for (int ni = 0; ni < 4; ++ni) {
            int col = n0 + ni * 16 + (lane & 15);
            float w3v = w3[col];
            float cbv = cb[col];
#pragma unroll
            for (int mi = 0; mi < 4; ++mi)
#pragma unroll
                for (int r = 0; r < 4; ++r)
                    rsum[mi][r] += fmaxf(acc[mi][ni][r] + cbv, 0.f) * w3v;
        }
#pragma unroll
        for (int mi = 0; mi < 4; ++mi)
#pragma unroll
            for (int r = 0; r < 4; ++r) {
                float s = rsum[mi][r];
                s += __shfl_xor(s, 1); s += __shfl_xor(s, 2);
                s += __shfl_xor(s, 4); s += __shfl_xor(s, 8);
                if ((lane & 15) == 0)
                    smF[wave][mi * 16 + (lane >> 4) * 4 + r] = s;
            }
        __syncthreads();
        if (tid < 64) {
            int row = m0 + tid;
            if (row < M) {
                float s = smF[0][tid] + smF[1][tid] + b3;
                outF[row] = 1.0f / (1.0f + expf(-s));
            }
        }
    }
}

// ---------------- launch ----------------

extern "C" void kernel_launch(void* const* d_in, const int* in_sizes, int n_in,
                              void* d_out, int out_size, void* d_ws, size_t ws_size,
                              hipStream_t stream) {
    const float* x = (const float*)d_in[0];
    const int* ei = (const int*)d_in[1];
    const int* src = ei;
    const int* dst = ei + NEDGES;
    const float* w_l[3] = {(const float*)d_in[2], (const float*)d_in[9], (const float*)d_in[16]};
    const float* b_l[3] = {(const float*)d_in[3], (const float*)d_in[10], (const float*)d_in[17]};
    const float* w_r[3] = {(const float*)d_in[4], (const float*)d_in[11], (const float*)d_in[18]};
    const float* g[3]  = {(const float*)d_in[5], (const float*)d_in[12], (const float*)d_in[19]};
    const float* be[3] = {(const float*)d_in[6], (const float*)d_in[13], (const float*)d_in[20]};
    const float* rm[3] = {(const float*)d_in[7], (const float*)d_in[14], (const float*)d_in[21]};
    const float* rv[3] = {(const float*)d_in[8], (const float*)d_in[15], (const float*)d_in[22]};
    const float* pw1 = (const float*)d_in[23]; const float* pb1 = (const float*)d_in[24];
    const float* pw2 = (const float*)d_in[25]; const float* pb2 = (const float*)d_in[26];
    const float* pw3 = (const float*)d_in[27]; const float* pb3 = (const float*)d_in[28];

    char* wsb = (char*)d_ws;
    size_t o = 0;
    auto alloc = [&](size_t b) { size_t r = o; o = (o + b + 255) & ~(size_t)255; return r; };

    int* deg    = (int*)(wsb + alloc(NNODES * 4));
    int* cursor = (int*)(wsb + alloc(NNODES * 4));
    int* poffs  = (int*)(wsb + alloc((NNODES + 1) * 4));
    int* bsum   = (int*)(wsb + alloc(256 * 4));
    int* csr    = (int*)(wsb + alloc((NEDGES + 8 * NNODES) * 4));   // padded CSR
    f16* h0   = (f16*)(wsb + alloc((size_t)(NNODES + 1) * 128 * 2)); // +1 zero pad row
    f16* hA   = (f16*)(wsb + alloc((size_t)(NNODES + 1) * 256 * 2));
    f16* hB   = (f16*)(wsb + alloc((size_t)(NNODES + 1) * 256 * 2));
    f16* mean = (f16*)(wsb + alloc((size_t)NNODES * 256 * 2));
    f16* wl0f = (f16*)(wsb + alloc(256 * 128 * 2));
    f16* wr0f = (f16*)(wsb + alloc(256 * 128 * 2));
    f16* wl1f = (f16*)(wsb + alloc(256 * 256 * 2));
    f16* wr1f = (f16*)(wsb + alloc(256 * 256 * 2));
    f16* wl2f = (f16*)(wsb + alloc(256 * 256 * 2));
    f16* wr2f = (f16*)(wsb + alloc(256 * 256 * 2));
    f16* pw1f = (f16*)(wsb + alloc(256 * 256 * 2));
    f16* pw2f = (f16*)(wsb + alloc(128 * 256 * 2));
    float* csv[5]; float* cbv[5];
    for (int i = 0; i < 5; ++i) {
        csv[i] = (float*)(wsb + alloc(256 * 4));
        cbv[i] = (float*)(wsb + alloc(256 * 4));
    }

    // --- CSR build (padded) ---
    hipMemsetAsync(deg, 0, NNODES * 4, stream);
    hipMemsetAsync(cursor, 0, NNODES * 4, stream);
    // zero feature rows for pad index NNODES
    hipMemsetAsync(h0 + (size_t)NNODES * 128, 0, 128 * 2, stream);
    hipMemsetAsync(hA + (size_t)NNODES * 256, 0, 256 * 2, stream);
    hipMemsetAsync(hB + (size_t)NNODES * 256, 0, 256 * 2, stream);
    k_deg<<<3125, 256, 0, stream>>>(dst, deg, NEDGES);
    int nb = (NNODES + 255) / 256;  // 196
    k_bsum<<<nb, 256, 0, stream>>>(deg, bsum, NNODES);
    k_scan_bsum<<<1, 64, 0, stream>>>(bsum, nb);
    k_offsets<<<nb, 256, 0, stream>>>(deg, bsum, poffs, NNODES);
    k_scatter<<<3125, 256, 0, stream>>>(src, dst, poffs, cursor, csr, NEDGES);
    k_pad<<<nb, 256, 0, stream>>>(deg, poffs, csr, NNODES);

    // --- all float->f16 conversions in one launch ---
    CvtArgs ca;
    ca.seg[0] = {x,      h0,   NNODES * 128 / 4};
    ca.seg[1] = {w_l[0], wl0f, 256 * 128 / 4};
    ca.seg[2] = {w_r[0], wr0f, 256 * 128 / 4};
    ca.seg[3] = {w_l[1], wl1f, 256 * 256 / 4};
    ca.seg[4] = {w_r[1], wr1f, 256 * 256 / 4};
    ca.seg[5] = {w_l[2], wl2f, 256 * 256 / 4};
    ca.seg[6] = {w_r[2], wr2f, 256 * 256 / 4};
    ca.seg[7] = {pw1,    pw1f, 256 * 256 / 4};
    ca.seg[8] = {pw2,    pw2f, 128 * 256 / 4};
    k_prep<<<2048, 256, 0, stream>>>(ca);

    AffArgs aa;
    for (int i = 0; i < 3; ++i)
        aa.s[i] = {b_l[i], g[i], be[i], rm[i], rv[i], csv[i], cbv[i], 256, 1};
    aa.s[3] = {pb1, nullptr, nullptr, nullptr, nullptr, csv[3], cbv[3], 256, 0};
    aa.s[4] = {pb2, nullptr, nullptr, nullptr, nullptr, csv[4], cbv[4], 128, 0};
    k_affine_all<<<5, 256, 0, stream>>>(aa);

    int gm = (NNODES + 63) / 64;  // 782

    // --- layer 0 (F_in=128) ---
    k_aggregate<128><<<3125, 256, 0, stream>>>(h0, poffs, deg, csr, mean);
    k_gemm<false><<<gm, 256, 0, stream>>>(mean, h0, wl0f, wr0f, csv[0], cbv[0], hA,
                                          nullptr, nullptr, nullptr, NNODES, 128, 256);
    // --- layer 1 ---
    k_aggregate<256><<<6250, 256, 0, stream>>>(hA, poffs, deg, csr, mean);
    k_gemm<false><<<gm, 256, 0, stream>>>(mean, hA, wl1f, wr1f, csv[1], cbv[1], hB,
                                          nullptr, nullptr, nullptr, NNODES, 256, 256);
    // --- layer 2 ---
    k_aggregate<256><<<6250, 256, 0, stream>>>(hB, poffs, deg, csr, mean);
    k_gemm<false><<<gm, 256, 0, stream>>>(mean, hB, wl2f, wr2f, csv[2], cbv[2], hA,
                                          nullptr, nullptr, nullptr, NNODES, 256, 256);
    // --- predictor ---
    k_gemm<false><<<gm, 256, 0, stream>>>(hA, nullptr, pw1f, nullptr, csv[3], cbv[3], hB,
                                          nullptr, nullptr, nullptr, NNODES, 256, 256);
    k_gemm<true><<<gm, 128, 0, stream>>>(hB, nullptr, pw2f, nullptr, csv[4], cbv[4], nullptr,
                                         pw3, pb3, (float*)d_out, NNODES, 256, 128);
}